// Round 10
// baseline (197.624 us; speedup 1.0000x reference)
//
#include <hip/hip_runtime.h>
#include <hip/hip_bf16.h>

typedef __bf16 bf16_t;
typedef __bf16 bf16x8 __attribute__((ext_vector_type(8)));
typedef float  f32x4  __attribute__((ext_vector_type(4)));

#define B_ 8
#define T_ 2048
#define C_ 1024
#define H_ 64

#define MFMA16(a, b, c) __builtin_amdgcn_mfma_f32_16x16x32_bf16((a), (b), (c), 0, 0, 0)
// async global->LDS, 16B per lane; dest = wave-uniform base + lane*16 (linear)
#define GLL16(g, l) __builtin_amdgcn_global_load_lds( \
    (const __attribute__((address_space(1))) unsigned int*)(g), \
    (__attribute__((address_space(3))) unsigned int*)(l), 16, 0, 0)
// RAW barrier: __syncthreads() lowers to s_waitcnt vmcnt(0) lgkmcnt(0) +
// s_barrier (drains prefetch).  Raw s_barrier + explicit counted s_waitcnt
// keeps next-tile loads in flight across the barrier.
#define SBAR() asm volatile("s_barrier" ::: "memory")

// ---------------------------------------------------------------------------
// Kernel 1: W fp32 -> hi/lo bf16 [192][1024] (q|k|v rows) + zero Oacc/lacc.
// ---------------------------------------------------------------------------
__global__ __launch_bounds__(256) void wconv_kernel(
    const float* __restrict__ Wk, const float* __restrict__ Wq,
    const float* __restrict__ Wv,
    bf16_t* __restrict__ Wh, bf16_t* __restrict__ Wl,
    f32x4* __restrict__ zero_dst)
{
    int i = blockIdx.x * 256 + threadIdx.x;
    zero_dst[i] = (f32x4){0.f, 0.f, 0.f, 0.f};      // 1040*256 = 266240 exact
    if (blockIdx.x < 768) {
        int r = i >> 10;
        int c = i & 1023;
        float v;
        if (r < 64)       v = Wq[r * 1024 + c];
        else if (r < 128) v = Wk[(r - 64) * 1024 + c];
        else              v = Wv[(r - 128) * 1024 + c];
        bf16_t h = (bf16_t)v;
        Wh[i] = h;
        Wl[i] = (bf16_t)(v - (float)h);
    }
}

// ---------------------------------------------------------------------------
// Kernel 2: QKV projection (R10: 2 co-resident blocks/CU).
// R9 left proj at 56 us with all pipes idle: 256 blocks = 1 block/CU, so both
// barriers expose whatever latency vmcnt doesn't cover -- no second block to
// fill the gap.  R10: M-tile 32, K-step 32 -> 512 blocks x 512 thr, LDS
// 2x24KB = 48 KB/block -> 2 blocks/CU co-resident; block A's stalls hide
// under block B's MFMAs (R4-attn proven).  Waves = 2 mhalf x 4 ncol(48),
// acc[3]; 3 GLLs/wave + 2 x-loads per iter, vmcnt(5), raw barriers.
// LDS layout: 24 lane-linear 1KB groups [mat(2) x nt(12)], conflict-free.
// ---------------------------------------------------------------------------
__global__ __launch_bounds__(512, 4) void proj_kernel(
    const float*  __restrict__ x,
    const bf16_t* __restrict__ Wh, const bf16_t* __restrict__ Wl,
    bf16_t* __restrict__ qh, bf16_t* __restrict__ ql,
    bf16_t* __restrict__ kh, bf16_t* __restrict__ kl,
    bf16_t* __restrict__ vh)
{
    __shared__ bf16_t Wlds[2][24][512];    // 48 KB, double-buffered

    const int tid   = threadIdx.x;
    const int wid   = tid >> 6;            // 0..7
    const int lane  = tid & 63;
    const int quad  = lane >> 4;
    const int l16   = lane & 15;
    const int mhalf = wid >> 2;            // 16-row group 0..1
    const int nq    = wid & 3;             // 48-col group 0..3
    const int g     = blockIdx.x * 32 + mhalf * 16 + l16;
    const float* xrow = x + (size_t)g * C_;

    // staging: wave w fills groups 3w..3w+2 of 24; grp = mat*12 + nt
    auto stage = [&](int k0, int bufi) {
        #pragma unroll
        for (int i = 0; i < 3; ++i) {
            int grp = wid * 3 + i;
            int mat = (grp >= 12);
            int nt  = grp - mat * 12;
            const bf16_t* src = (mat ? Wl : Wh) + (nt * 16 + l16) * 1024 + k0 + quad * 8;
            GLL16(src, &Wlds[bufi][grp][0]);
        }
    };
    // x chunk it = k cols [it*32, it*32+32): 8 floats per lane
    auto loadx = [&](int it, f32x4* d) {
        d[0] = *(const f32x4*)(xrow + it * 32 + quad * 8);
        d[1] = *(const f32x4*)(xrow + it * 32 + quad * 8 + 4);
    };

    stage(0, 0);
    f32x4 x0[2], x1[2];
    loadx(0, x0);
    loadx(1, x1);

    f32x4 acc[3];
    #pragma unroll
    for (int i = 0; i < 3; ++i) acc[i] = (f32x4){0.f, 0.f, 0.f, 0.f};

    int buf = 0;
    for (int it = 0; it < 32; ++it) {
        float xv[8];
        *(f32x4*)(xv)     = x0[0];
        *(f32x4*)(xv + 4) = x0[1];
        x0[0] = x1[0]; x0[1] = x1[1];

        if (it + 1 < 32) {
            stage((it + 1) * 32, buf ^ 1);
            if (it + 2 < 32) {
                loadx(it + 2, x1);
                asm volatile("s_waitcnt vmcnt(5)" ::: "memory");
            } else {
                asm volatile("s_waitcnt vmcnt(3)" ::: "memory");
            }
        } else {
            asm volatile("s_waitcnt vmcnt(0)" ::: "memory");
        }
        SBAR();                            // raw: prefetch stays in flight

        bf16x8 ah, al;
        #pragma unroll
        for (int jj = 0; jj < 8; ++jj) {
            bf16_t h = (bf16_t)xv[jj];
            ah[jj] = h;
            al[jj] = (bf16_t)(xv[jj] - (float)h);
        }

        #pragma unroll
        for (int nt = 0; nt < 3; ++nt) {
            int gi = nq * 3 + nt;
            bf16x8 bh = *(const bf16x8*)(&Wlds[buf][gi][lane * 8]);
            bf16x8 bl = *(const bf16x8*)(&Wlds[buf][gi + 12][lane * 8]);
            acc[nt] = MFMA16(ah, bh, acc[nt]);
            acc[nt] = MFMA16(ah, bl, acc[nt]);
            acc[nt] = MFMA16(al, bh, acc[nt]);
        }

        SBAR();                            // protect buf before re-staging
        buf ^= 1;
    }

    // epilogue: D layout col=lane&15, row=quad*4+reg
    const int rowbase = blockIdx.x * 32 + mhalf * 16 + quad * 4;
    for (int nt = 0; nt < 3; ++nt) {
        int n = (nq * 3 + nt) * 16 + l16;
        for (int rr = 0; rr < 4; ++rr) {
            int grow = rowbase + rr;
            int bb = grow >> 11, t = grow & 2047;
            float v  = acc[nt][rr];
            bf16_t h = (bf16_t)v;
            if (n < 64) {
                int off = (bb * T_ + t) * H_ + n;
                qh[off] = h; ql[off] = (bf16_t)(v - (float)h);
            } else if (n < 128) {
                int off = (bb * T_ + t) * H_ + (n - 64);
                kh[off] = h; kl[off] = (bf16_t)(v - (float)h);
            } else {
                vh[(bb * H_ + (n - 128)) * T_ + t] = h;
            }
        }
    }
}

// ---------------------------------------------------------------------------
// Kernel 3: attention (unchanged R9: raw barriers, counted vmcnt).
// ---------------------------------------------------------------------------
__global__ __launch_bounds__(512, 4) void attn_kernel(
    const bf16_t* __restrict__ qh, const bf16_t* __restrict__ ql,
    const bf16_t* __restrict__ kh, const bf16_t* __restrict__ kl,
    const bf16_t* __restrict__ vh,
    float* __restrict__ Oacc, float* __restrict__ lacc)
{
    __shared__ bf16_t KV[2][3][4096];     // [dbuf][kh|kl|v][64x64] = 48 KB
    __shared__ bf16_t Plds[8][16 * 72];   // per-wave P buffer, 18 KB

    const int tid  = threadIdx.x;
    const int wid  = tid >> 6;
    const int lane = tid & 63;
    const int quad = lane >> 4;
    const int l16  = lane & 15;

    const int b  = blockIdx.x & 7;         // XCD-aligned batch
    const int gp = (blockIdx.x >> 3) & 7;  // pair index
    const int s  = blockIdx.x >> 6;        // j-slice 0..7
    const int gA = gp, gB = 15 - gp;
    const int nA = 2 * gA + 2;             // j-steps of tile A (tile B: 34-nA)

    const int t_nt   = wid >> 1;
    const int t_kk   = wid & 1;
    const int t_l16  = tid & 15;
    const int t_quad = (tid >> 4) & 3;
    const int koff   = (t_nt * 16 + t_l16) * H_ + t_kk * 32 + t_quad * 8;
    const int voff   = (t_nt * 16 + t_l16) * T_ + t_kk * 32 + t_quad * 8;

    auto stage = [&](int j, int bufi) {
        const size_t kbase = (size_t)(b * T_ + 64 * j) * H_;
        GLL16(kh + kbase + koff, &KV[bufi][0][wid * 512]);
        GLL16(kl + kbase + koff, &KV[bufi][1][wid * 512]);
        GLL16(vh + (size_t)b * H_ * T_ + 64 * j + voff, &KV[bufi][2][wid * 512]);
    };

    f32x4  O[4];
    float  rowsum[4];
    bf16x8 aqh[2], aql[2];
    int    gcur = -1;

    auto flushO = [&]() {
        #pragma unroll
        for (int rr = 0; rr < 4; ++rr) {
            int trow = b * T_ + 128 * gcur + 16 * wid + quad * 4 + rr;
            #pragma unroll
            for (int ht = 0; ht < 4; ++ht)
                atomicAdd(Oacc + (size_t)trow * H_ + ht * 16 + l16, O[ht][rr]);
            float s_ = rowsum[rr];
            s_ += __shfl_xor(s_, 1, 64);
            s_ += __shfl_xor(s_, 2, 64);
            s_ += __shfl_xor(s_, 4, 64);
            s_ += __shfl_xor(s_, 8, 64);
            if (l16 == 0) atomicAdd(lacc + trow, s_);
        }
    };

    {
        int u0 = s;
        int j0 = (u0 < nA) ? u0 : (u0 - nA);
        stage(j0, 0);
    }

    int buf = 0;
    for (int u = s; u < 34; u += 8) {
        const int g = (u < nA) ? gA : gB;
        const int j = (u < nA) ? u : (u - nA);

        const int un = u + 8;
        if (un < 34) {
            int jn = (un < nA) ? un : (un - nA);
            stage(jn, buf ^ 1);
            asm volatile("s_waitcnt vmcnt(3)" ::: "memory");
        } else {
            asm volatile("s_waitcnt vmcnt(0)" ::: "memory");
        }
        SBAR();                            // raw: next K/V stays in flight

        if (g != gcur) {
            if (gcur >= 0) flushO();
            gcur = g;
            const size_t qoff = (size_t)(b * T_ + 128 * g + 16 * wid + l16) * H_;
            #pragma unroll
            for (int kk = 0; kk < 2; ++kk) {
                aqh[kk] = *(const bf16x8*)(qh + qoff + kk * 32 + quad * 8);
                aql[kk] = *(const bf16x8*)(ql + qoff + kk * 32 + quad * 8);
            }
            #pragma unroll
            for (int i = 0; i < 4; ++i) { O[i] = (f32x4){0.f,0.f,0.f,0.f}; rowsum[i] = 0.f; }
        }

        const bf16_t* Kh = KV[buf][0];
        const bf16_t* Kl = KV[buf][1];
        f32x4 S[4];
        #pragma unroll
        for (int i = 0; i < 4; ++i) S[i] = (f32x4){0.f,0.f,0.f,0.f};
        #pragma unroll
        for (int nt = 0; nt < 4; ++nt) {
            #pragma unroll
            for (int kk = 0; kk < 2; ++kk) {
                bf16x8 bh = *(const bf16x8*)(Kh + (nt * 2 + kk) * 512 + lane * 8);
                bf16x8 bl = *(const bf16x8*)(Kl + (nt * 2 + kk) * 512 + lane * 8);
                S[nt] = MFMA16(aqh[kk], bh, S[nt]);
                S[nt] = MFMA16(aqh[kk], bl, S[nt]);
                S[nt] = MFMA16(aql[kk], bh, S[nt]);
            }
        }

        bf16_t* Pw = Plds[wid];
        const int rloc = 128 * g + 16 * wid + quad * 4;
        #pragma unroll
        for (int nt = 0; nt < 4; ++nt) {
            int colt = 64 * j + nt * 16 + l16;
            #pragma unroll
            for (int rr = 0; rr < 4; ++rr) {
                float pv = (colt <= rloc + rr)
                         ? __expf(fmaf(S[nt][rr], 0.125f, -20.0f)) : 0.f;
                rowsum[rr] += pv;
                Pw[(quad * 4 + rr) * 72 + nt * 16 + l16] = (bf16_t)pv;
            }
        }

        bf16x8 ap0 = *(const bf16x8*)(Pw + l16 * 72 + quad * 8);
        bf16x8 ap1 = *(const bf16x8*)(Pw + l16 * 72 + 32 + quad * 8);

        const bf16_t* Vt = KV[buf][2];
        #pragma unroll
        for (int ht = 0; ht < 4; ++ht) {
            bf16x8 bv0 = *(const bf16x8*)(Vt + (ht * 2 + 0) * 512 + lane * 8);
            bf16x8 bv1 = *(const bf16x8*)(Vt + (ht * 2 + 1) * 512 + lane * 8);
            O[ht] = MFMA16(ap0, bv0, O[ht]);
            O[ht] = MFMA16(ap1, bv1, O[ht]);
        }

        SBAR();                            // done reading buf before re-stage
        buf ^= 1;
    }
    if (gcur >= 0) flushO();
}

// ---------------------------------------------------------------------------
// Kernel 4: out = Oacc / lacc
// ---------------------------------------------------------------------------
__global__ __launch_bounds__(256) void div_kernel(
    const float* __restrict__ Oacc, const float* __restrict__ lacc,
    float* __restrict__ out)
{
    int i = blockIdx.x * 256 + threadIdx.x;          // f32x4 index, 262144 total
    f32x4 o   = ((const f32x4*)Oacc)[i];
    float inv = 1.0f / lacc[i >> 4];
    ((f32x4*)out)[i] = o * inv;
}

// ---------------------------------------------------------------------------
extern "C" void kernel_launch(void* const* d_in, const int* in_sizes, int n_in,
                              void* d_out, int out_size, void* d_ws, size_t ws_size,
                              hipStream_t stream)
{
    const float* x  = (const float*)d_in[0];
    const float* Wk = (const float*)d_in[1];
    const float* Wq = (const float*)d_in[2];
    const float* Wv = (const float*)d_in[3];
    float* out = (float*)d_out;

    char* ws = (char*)d_ws;
    const size_t WSZ = 192 * 1024 * sizeof(bf16_t);            // 393216
    const size_t QSZ = (size_t)B_ * T_ * H_ * sizeof(bf16_t);  // 2097152
    bf16_t* Wh   = (bf16_t*)(ws);
    bf16_t* Wl   = (bf16_t*)(ws + WSZ);
    bf16_t* qh   = (bf16_t*)(ws + 2 * WSZ);
    bf16_t* ql   = (bf16_t*)(ws + 2 * WSZ + 1 * QSZ);
    bf16_t* kh   = (bf16_t*)(ws + 2 * WSZ + 2 * QSZ);
    bf16_t* kl   = (bf16_t*)(ws + 2 * WSZ + 3 * QSZ);
    bf16_t* vh   = (bf16_t*)(ws + 2 * WSZ + 4 * QSZ);
    float*  Oacc = (float*)(ws + 2 * WSZ + 5 * QSZ);           // 4 MB
    float*  lacc = (float*)(ws + 2 * WSZ + 5 * QSZ + (size_t)B_ * T_ * H_ * 4);

    hipLaunchKernelGGL(wconv_kernel, dim3(1040), dim3(256), 0, stream,
                       Wk, Wq, Wv, Wh, Wl, (f32x4*)Oacc);
    hipLaunchKernelGGL(proj_kernel, dim3(512), dim3(512), 0, stream,
                       x, Wh, Wl, qh, ql, kh, kl, vh);
    hipLaunchKernelGGL(attn_kernel, dim3(512), dim3(512), 0, stream,
                       qh, ql, kh, kl, vh, Oacc, lacc);
    hipLaunchKernelGGL(div_kernel, dim3(1024), dim3(256), 0, stream, Oacc, lacc, out);
}

// Round 11
// 170.049 us; speedup vs baseline: 1.1622x; 1.1622x over previous
//
#include <hip/hip_runtime.h>
#include <hip/hip_bf16.h>

typedef __bf16 bf16_t;
typedef __bf16 bf16x8 __attribute__((ext_vector_type(8)));
typedef float  f32x4  __attribute__((ext_vector_type(4)));

#define B_ 8
#define T_ 2048
#define C_ 1024
#define H_ 64

#define MFMA16(a, b, c) __builtin_amdgcn_mfma_f32_16x16x32_bf16((a), (b), (c), 0, 0, 0)
// async global->LDS, 16B per lane; dest = wave-uniform base + lane*16 (linear)
#define GLL16(g, l) __builtin_amdgcn_global_load_lds( \
    (const __attribute__((address_space(1))) unsigned int*)(g), \
    (__attribute__((address_space(3))) unsigned int*)(l), 16, 0, 0)
// RAW barrier: __syncthreads() lowers to s_waitcnt vmcnt(0) lgkmcnt(0) +
// s_barrier (drains prefetch).  Raw s_barrier + explicit counted s_waitcnt
// keeps next-tile loads in flight across the barrier.
#define SBAR() asm volatile("s_barrier" ::: "memory")
// compiler-only ordering fence (no instruction): pins VM issue order so
// in-order vmcnt retirement matches the schedule below.
#define CFENCE() asm volatile("" ::: "memory")

// ---------------------------------------------------------------------------
// Kernel 1: W fp32 -> hi/lo bf16 [192][1024] (q|k|v rows) + zero Oacc/lacc.
// ---------------------------------------------------------------------------
__global__ __launch_bounds__(256) void wconv_kernel(
    const float* __restrict__ Wk, const float* __restrict__ Wq,
    const float* __restrict__ Wv,
    bf16_t* __restrict__ Wh, bf16_t* __restrict__ Wl,
    f32x4* __restrict__ zero_dst)
{
    int i = blockIdx.x * 256 + threadIdx.x;
    zero_dst[i] = (f32x4){0.f, 0.f, 0.f, 0.f};      // 1040*256 = 266240 exact
    if (blockIdx.x < 768) {
        int r = i >> 10;
        int c = i & 1023;
        float v;
        if (r < 64)       v = Wq[r * 1024 + c];
        else if (r < 128) v = Wk[(r - 64) * 1024 + c];
        else              v = Wv[(r - 128) * 1024 + c];
        bf16_t h = (bf16_t)v;
        Wh[i] = h;
        Wl[i] = (bf16_t)(v - (float)h);
    }
}

// ---------------------------------------------------------------------------
// Kernel 2: QKV projection (R11 = R9 geometry + VM issue-order fix).
// R9's residual stall: issue order was stage(GLLs) THEN loadx; vmcnt retires
// IN ORDER, so the next iteration's x0=x1 copy (compiler-inserted wait on the
// NEWEST ops = the x loads) drained the whole queue including the prefetch
// GLLs -> explicit vmcnt(10) was a no-op, GLL latency fully exposed.
// R11: loadx BEFORE stage (CFENCE pins it).  Top-of-loop x-wait now drains
// only up to the x loads; vmcnt(10) {= 6 new GLL + 4 x} drains exactly the
// current tile's GLLs after one full interval in flight.
// Geometry (R9): M-tile 64, K-step 64, 256 blk x 512 thr, 96 KB dbuf,
// 16 iters, conflict-free lane-linear LDS (measured 0 conflicts).
// ---------------------------------------------------------------------------
__global__ __launch_bounds__(512, 2) void proj_kernel(
    const float*  __restrict__ x,
    const bf16_t* __restrict__ Wh, const bf16_t* __restrict__ Wl,
    bf16_t* __restrict__ qh, bf16_t* __restrict__ ql,
    bf16_t* __restrict__ kh, bf16_t* __restrict__ kl,
    bf16_t* __restrict__ vh)
{
    __shared__ bf16_t Wlds[2][48][512];    // 96 KB, double-buffered

    const int tid   = threadIdx.x;
    const int wid   = tid >> 6;            // 0..7
    const int lane  = tid & 63;
    const int quad  = lane >> 4;
    const int l16   = lane & 15;
    const int mhalf = wid >> 1;            // 16-row group 0..3
    const int nhalf = wid & 1;             // 96-col group
    const int g     = blockIdx.x * 64 + mhalf * 16 + l16;
    const float* xrow = x + (size_t)g * C_;

    // staging: wave w fills groups 6w..6w+5 of 48; grp = ksub*24 + mat*12 + nt
    auto stage = [&](int k0, int bufi) {
        #pragma unroll
        for (int i = 0; i < 6; ++i) {
            int grp  = wid * 6 + i;
            int ksub = (grp >= 24);
            int rem  = grp - ksub * 24;
            int mat  = (rem >= 12);
            int nt   = rem - mat * 12;
            const bf16_t* src = (mat ? Wl : Wh)
                + (nt * 16 + l16) * 1024 + k0 + ksub * 32 + quad * 8;
            GLL16(src, &Wlds[bufi][grp][0]);
        }
    };
    // x chunk it = k cols [it*64, it*64+64): per lane 2 ksubs x 8 floats
    auto loadx = [&](int it, f32x4* d) {
        #pragma unroll
        for (int ks = 0; ks < 2; ++ks) {
            d[ks * 2]     = *(const f32x4*)(xrow + it * 64 + ks * 32 + quad * 8);
            d[ks * 2 + 1] = *(const f32x4*)(xrow + it * 64 + ks * 32 + quad * 8 + 4);
        }
    };

    // prologue: x loads FIRST (older than GLLs in the vm queue)
    f32x4 x0[4], x1[4];
    loadx(0, x0);
    loadx(1, x1);
    CFENCE();
    stage(0, 0);

    f32x4 acc[6];
    #pragma unroll
    for (int i = 0; i < 6; ++i) acc[i] = (f32x4){0.f, 0.f, 0.f, 0.f};

    int buf = 0;
    for (int it = 0; it < 16; ++it) {
        float xv[16];
        *(f32x4*)(xv)      = x0[0];
        *(f32x4*)(xv + 4)  = x0[1];
        *(f32x4*)(xv + 8)  = x0[2];
        *(f32x4*)(xv + 12) = x0[3];
        #pragma unroll
        for (int i = 0; i < 4; ++i) x0[i] = x1[i];

        if (it + 1 < 16) {
            if (it + 2 < 16) {
                loadx(it + 2, x1);         // x BEFORE stage: older in queue
                CFENCE();
                stage((it + 1) * 64, buf ^ 1);
                // queue: GLL(it) x6 | x(it+2) x4 | GLL(it+1) x6 = 16
                // keep 10 newest -> drain exactly GLL(it), tile now consumed
                asm volatile("s_waitcnt vmcnt(10)" ::: "memory");
            } else {
                CFENCE();
                stage((it + 1) * 64, buf ^ 1);
                asm volatile("s_waitcnt vmcnt(6)" ::: "memory");
            }
        } else {
            asm volatile("s_waitcnt vmcnt(0)" ::: "memory");
        }
        SBAR();                            // raw: prefetch stays in flight

        #pragma unroll
        for (int ks = 0; ks < 2; ++ks) {
            bf16x8 ah, al;
            #pragma unroll
            for (int jj = 0; jj < 8; ++jj) {
                float  xf = xv[ks * 8 + jj];
                bf16_t h  = (bf16_t)xf;
                ah[jj] = h;
                al[jj] = (bf16_t)(xf - (float)h);
            }
            #pragma unroll
            for (int nt = 0; nt < 6; ++nt) {
                int gi = ks * 24 + nhalf * 6 + nt;
                bf16x8 bh = *(const bf16x8*)(&Wlds[buf][gi][lane * 8]);
                bf16x8 bl = *(const bf16x8*)(&Wlds[buf][gi + 12][lane * 8]);
                acc[nt] = MFMA16(ah, bh, acc[nt]);
                acc[nt] = MFMA16(ah, bl, acc[nt]);
                acc[nt] = MFMA16(al, bh, acc[nt]);
            }
        }

        SBAR();                            // protect buf before re-staging
        buf ^= 1;
    }

    // epilogue: D layout col=lane&15, row=quad*4+reg
    const int rowbase = blockIdx.x * 64 + mhalf * 16 + quad * 4;
    for (int nt = 0; nt < 6; ++nt) {
        int n = (nhalf * 6 + nt) * 16 + l16;
        for (int rr = 0; rr < 4; ++rr) {
            int grow = rowbase + rr;
            int bb = grow >> 11, t = grow & 2047;
            float v  = acc[nt][rr];
            bf16_t h = (bf16_t)v;
            if (n < 64) {
                int off = (bb * T_ + t) * H_ + n;
                qh[off] = h; ql[off] = (bf16_t)(v - (float)h);
            } else if (n < 128) {
                int off = (bb * T_ + t) * H_ + (n - 64);
                kh[off] = h; kl[off] = (bf16_t)(v - (float)h);
            } else {
                vh[(bb * H_ + (n - 128)) * T_ + t] = h;
            }
        }
    }
}

// ---------------------------------------------------------------------------
// Kernel 3: attention (unchanged: raw barriers, counted vmcnt).
// ---------------------------------------------------------------------------
__global__ __launch_bounds__(512, 4) void attn_kernel(
    const bf16_t* __restrict__ qh, const bf16_t* __restrict__ ql,
    const bf16_t* __restrict__ kh, const bf16_t* __restrict__ kl,
    const bf16_t* __restrict__ vh,
    float* __restrict__ Oacc, float* __restrict__ lacc)
{
    __shared__ bf16_t KV[2][3][4096];     // [dbuf][kh|kl|v][64x64] = 48 KB
    __shared__ bf16_t Plds[8][16 * 72];   // per-wave P buffer, 18 KB

    const int tid  = threadIdx.x;
    const int wid  = tid >> 6;
    const int lane = tid & 63;
    const int quad = lane >> 4;
    const int l16  = lane & 15;

    const int b  = blockIdx.x & 7;         // XCD-aligned batch
    const int gp = (blockIdx.x >> 3) & 7;  // pair index
    const int s  = blockIdx.x >> 6;        // j-slice 0..7
    const int gA = gp, gB = 15 - gp;
    const int nA = 2 * gA + 2;             // j-steps of tile A (tile B: 34-nA)

    const int t_nt   = wid >> 1;
    const int t_kk   = wid & 1;
    const int t_l16  = tid & 15;
    const int t_quad = (tid >> 4) & 3;
    const int koff   = (t_nt * 16 + t_l16) * H_ + t_kk * 32 + t_quad * 8;
    const int voff   = (t_nt * 16 + t_l16) * T_ + t_kk * 32 + t_quad * 8;

    auto stage = [&](int j, int bufi) {
        const size_t kbase = (size_t)(b * T_ + 64 * j) * H_;
        GLL16(kh + kbase + koff, &KV[bufi][0][wid * 512]);
        GLL16(kl + kbase + koff, &KV[bufi][1][wid * 512]);
        GLL16(vh + (size_t)b * H_ * T_ + 64 * j + voff, &KV[bufi][2][wid * 512]);
    };

    f32x4  O[4];
    float  rowsum[4];
    bf16x8 aqh[2], aql[2];
    int    gcur = -1;

    auto flushO = [&]() {
        #pragma unroll
        for (int rr = 0; rr < 4; ++rr) {
            int trow = b * T_ + 128 * gcur + 16 * wid + quad * 4 + rr;
            #pragma unroll
            for (int ht = 0; ht < 4; ++ht)
                atomicAdd(Oacc + (size_t)trow * H_ + ht * 16 + l16, O[ht][rr]);
            float s_ = rowsum[rr];
            s_ += __shfl_xor(s_, 1, 64);
            s_ += __shfl_xor(s_, 2, 64);
            s_ += __shfl_xor(s_, 4, 64);
            s_ += __shfl_xor(s_, 8, 64);
            if (l16 == 0) atomicAdd(lacc + trow, s_);
        }
    };

    {
        int u0 = s;
        int j0 = (u0 < nA) ? u0 : (u0 - nA);
        stage(j0, 0);
    }

    int buf = 0;
    for (int u = s; u < 34; u += 8) {
        const int g = (u < nA) ? gA : gB;
        const int j = (u < nA) ? u : (u - nA);

        const int un = u + 8;
        if (un < 34) {
            int jn = (un < nA) ? un : (un - nA);
            stage(jn, buf ^ 1);
            asm volatile("s_waitcnt vmcnt(3)" ::: "memory");
        } else {
            asm volatile("s_waitcnt vmcnt(0)" ::: "memory");
        }
        SBAR();                            // raw: next K/V stays in flight

        if (g != gcur) {
            if (gcur >= 0) flushO();
            gcur = g;
            const size_t qoff = (size_t)(b * T_ + 128 * g + 16 * wid + l16) * H_;
            #pragma unroll
            for (int kk = 0; kk < 2; ++kk) {
                aqh[kk] = *(const bf16x8*)(qh + qoff + kk * 32 + quad * 8);
                aql[kk] = *(const bf16x8*)(ql + qoff + kk * 32 + quad * 8);
            }
            #pragma unroll
            for (int i = 0; i < 4; ++i) { O[i] = (f32x4){0.f,0.f,0.f,0.f}; rowsum[i] = 0.f; }
        }

        const bf16_t* Kh = KV[buf][0];
        const bf16_t* Kl = KV[buf][1];
        f32x4 S[4];
        #pragma unroll
        for (int i = 0; i < 4; ++i) S[i] = (f32x4){0.f,0.f,0.f,0.f};
        #pragma unroll
        for (int nt = 0; nt < 4; ++nt) {
            #pragma unroll
            for (int kk = 0; kk < 2; ++kk) {
                bf16x8 bh = *(const bf16x8*)(Kh + (nt * 2 + kk) * 512 + lane * 8);
                bf16x8 bl = *(const bf16x8*)(Kl + (nt * 2 + kk) * 512 + lane * 8);
                S[nt] = MFMA16(aqh[kk], bh, S[nt]);
                S[nt] = MFMA16(aqh[kk], bl, S[nt]);
                S[nt] = MFMA16(aql[kk], bh, S[nt]);
            }
        }

        bf16_t* Pw = Plds[wid];
        const int rloc = 128 * g + 16 * wid + quad * 4;
        #pragma unroll
        for (int nt = 0; nt < 4; ++nt) {
            int colt = 64 * j + nt * 16 + l16;
            #pragma unroll
            for (int rr = 0; rr < 4; ++rr) {
                float pv = (colt <= rloc + rr)
                         ? __expf(fmaf(S[nt][rr], 0.125f, -20.0f)) : 0.f;
                rowsum[rr] += pv;
                Pw[(quad * 4 + rr) * 72 + nt * 16 + l16] = (bf16_t)pv;
            }
        }

        bf16x8 ap0 = *(const bf16x8*)(Pw + l16 * 72 + quad * 8);
        bf16x8 ap1 = *(const bf16x8*)(Pw + l16 * 72 + 32 + quad * 8);

        const bf16_t* Vt = KV[buf][2];
        #pragma unroll
        for (int ht = 0; ht < 4; ++ht) {
            bf16x8 bv0 = *(const bf16x8*)(Vt + (ht * 2 + 0) * 512 + lane * 8);
            bf16x8 bv1 = *(const bf16x8*)(Vt + (ht * 2 + 1) * 512 + lane * 8);
            O[ht] = MFMA16(ap0, bv0, O[ht]);
            O[ht] = MFMA16(ap1, bv1, O[ht]);
        }

        SBAR();                            // done reading buf before re-stage
        buf ^= 1;
    }
    if (gcur >= 0) flushO();
}

// ---------------------------------------------------------------------------
// Kernel 4: out = Oacc / lacc
// ---------------------------------------------------------------------------
__global__ __launch_bounds__(256) void div_kernel(
    const float* __restrict__ Oacc, const float* __restrict__ lacc,
    float* __restrict__ out)
{
    int i = blockIdx.x * 256 + threadIdx.x;          // f32x4 index, 262144 total
    f32x4 o   = ((const f32x4*)Oacc)[i];
    float inv = 1.0f / lacc[i >> 4];
    ((f32x4*)out)[i] = o * inv;
}

// ---------------------------------------------------------------------------
extern "C" void kernel_launch(void* const* d_in, const int* in_sizes, int n_in,
                              void* d_out, int out_size, void* d_ws, size_t ws_size,
                              hipStream_t stream)
{
    const float* x  = (const float*)d_in[0];
    const float* Wk = (const float*)d_in[1];
    const float* Wq = (const float*)d_in[2];
    const float* Wv = (const float*)d_in[3];
    float* out = (float*)d_out;

    char* ws = (char*)d_ws;
    const size_t WSZ = 192 * 1024 * sizeof(bf16_t);            // 393216
    const size_t QSZ = (size_t)B_ * T_ * H_ * sizeof(bf16_t);  // 2097152
    bf16_t* Wh   = (bf16_t*)(ws);
    bf16_t* Wl   = (bf16_t*)(ws + WSZ);
    bf16_t* qh   = (bf16_t*)(ws + 2 * WSZ);
    bf16_t* ql   = (bf16_t*)(ws + 2 * WSZ + 1 * QSZ);
    bf16_t* kh   = (bf16_t*)(ws + 2 * WSZ + 2 * QSZ);
    bf16_t* kl   = (bf16_t*)(ws + 2 * WSZ + 3 * QSZ);
    bf16_t* vh   = (bf16_t*)(ws + 2 * WSZ + 4 * QSZ);
    float*  Oacc = (float*)(ws + 2 * WSZ + 5 * QSZ);           // 4 MB
    float*  lacc = (float*)(ws + 2 * WSZ + 5 * QSZ + (size_t)B_ * T_ * H_ * 4);

    hipLaunchKernelGGL(wconv_kernel, dim3(1040), dim3(256), 0, stream,
                       Wk, Wq, Wv, Wh, Wl, (f32x4*)Oacc);
    hipLaunchKernelGGL(proj_kernel, dim3(256), dim3(512), 0, stream,
                       x, Wh, Wl, qh, ql, kh, kl, vh);
    hipLaunchKernelGGL(attn_kernel, dim3(512), dim3(512), 0, stream,
                       qh, ql, kh, kl, vh, Oacc, lacc);
    hipLaunchKernelGGL(div_kernel, dim3(1024), dim3(256), 0, stream, Oacc, lacc, out);
}

// Round 12
// 163.813 us; speedup vs baseline: 1.2064x; 1.0381x over previous
//
#include <hip/hip_runtime.h>
#include <hip/hip_bf16.h>

typedef __bf16 bf16_t;
typedef __bf16 bf16x8 __attribute__((ext_vector_type(8)));
typedef float  f32x4  __attribute__((ext_vector_type(4)));

#define B_ 8
#define T_ 2048
#define C_ 1024
#define H_ 64

#define MFMA16(a, b, c) __builtin_amdgcn_mfma_f32_16x16x32_bf16((a), (b), (c), 0, 0, 0)
// async global->LDS, 16B per lane; dest = wave-uniform base + lane*16 (linear)
#define GLL16(g, l) __builtin_amdgcn_global_load_lds( \
    (const __attribute__((address_space(1))) unsigned int*)(g), \
    (__attribute__((address_space(3))) unsigned int*)(l), 16, 0, 0)
// RAW barrier: __syncthreads() lowers to s_waitcnt vmcnt(0) lgkmcnt(0) +
// s_barrier (drains prefetch).  Raw s_barrier + explicit counted s_waitcnt
// keeps loads in flight across the barrier.
#define SBAR() asm volatile("s_barrier" ::: "memory")

// ---------------------------------------------------------------------------
// Kernel 1: QKV projection with FUSED W conversion (R12).
// - wconv is gone: each block reg-stages its W fp32 K-tile (48 KB/iter),
//   converts to hi/lo bf16 in VALU, ds_writes into the SAME conflict-free
//   lane-linear layout as before (bit-identical results).
// - 3-slot LDS rotation (3 x 48 KB = 144 KB) -> ONE raw barrier per iter:
//   slot written at iter it was last read at iter it-2 (two barriers ago),
//   so the trailing barrier of the 2-slot scheme is unnecessary.
// - All VM waits land on loads issued one full interval earlier (T14
//   issue-early/write-late); no vmcnt counting games needed.
// - Oacc/lacc zeroing moved to the epilogue (after the loop, so the in-loop
//   vmcnt discipline never sees stores).
// Geometry: M-tile 64, K-step 64, 256 blocks x 512 threads, 16 iterations.
// ---------------------------------------------------------------------------
__global__ __launch_bounds__(512, 2) void proj_kernel(
    const float* __restrict__ x,
    const float* __restrict__ Wk, const float* __restrict__ Wq,
    const float* __restrict__ Wv,
    bf16_t* __restrict__ qh, bf16_t* __restrict__ ql,
    bf16_t* __restrict__ kh, bf16_t* __restrict__ kl,
    bf16_t* __restrict__ vh,
    f32x4* __restrict__ zero_dst)
{
    __shared__ bf16_t Wlds[3][48][512];    // 144 KB, 3-slot rotation

    const int tid   = threadIdx.x;
    const int wid   = tid >> 6;            // 0..7
    const int lane  = tid & 63;
    const int quad  = lane >> 4;
    const int l16   = lane & 15;
    const int mhalf = wid >> 1;            // 16-row group 0..3
    const int nhalf = wid & 1;             // 96-col group
    const int g     = blockIdx.x * 64 + mhalf * 16 + l16;
    const float* xrow = x + (size_t)g * C_;

    // --- W chunk mapping: 1536 chunks of 8 fp32; thread handles ci=tid+512*i.
    // ci -> ksub (k 32-half), nt (16-row group 0..11), ln (lane slot 0..63):
    // W row = nt*16 + (ln&15), fp32 col = k0 + ksub*32 + (ln>>4)*8.
    // LDS dest: hi group ksub*24+nt, lo group ksub*24+12+nt, elem ln*8
    // (identical layout to R9/R11 GLL version -> reader unchanged).
    const float* ck_src[3];
    int          ck_hi[3], ck_lo[3];
    #pragma unroll
    for (int i = 0; i < 3; ++i) {
        int ci   = tid + 512 * i;
        int ksub = ci / 768;
        int r    = ci - ksub * 768;
        int nt   = r >> 6;
        int ln   = r & 63;
        int row  = nt * 16 + (ln & 15);
        const float* base;
        if (row < 64)       base = Wq + row * 1024;
        else if (row < 128) base = Wk + (row - 64) * 1024;
        else                base = Wv + (row - 128) * 1024;
        ck_src[i] = base + ksub * 32 + (ln >> 4) * 8;
        ck_hi[i]  = (ksub * 24 + nt) * 512 + ln * 8;
        ck_lo[i]  = (ksub * 24 + 12 + nt) * 512 + ln * 8;
    }

    f32x4 wr[6];
    auto loadW = [&](int it) {
        #pragma unroll
        for (int i = 0; i < 3; ++i) {
            wr[i * 2]     = *(const f32x4*)(ck_src[i] + it * 64);
            wr[i * 2 + 1] = *(const f32x4*)(ck_src[i] + it * 64 + 4);
        }
    };
    auto convertWrite = [&](int slot) {
        bf16_t* L = &Wlds[slot][0][0];
        #pragma unroll
        for (int i = 0; i < 3; ++i) {
            float wf[8];
            *(f32x4*)(wf)     = wr[i * 2];
            *(f32x4*)(wf + 4) = wr[i * 2 + 1];
            bf16x8 hv, lv;
            #pragma unroll
            for (int j = 0; j < 8; ++j) {
                bf16_t h = (bf16_t)wf[j];
                hv[j] = h;
                lv[j] = (bf16_t)(wf[j] - (float)h);
            }
            *(bf16x8*)(L + ck_hi[i]) = hv;
            *(bf16x8*)(L + ck_lo[i]) = lv;
        }
    };
    auto loadx = [&](int it, f32x4* d) {
        #pragma unroll
        for (int ks = 0; ks < 2; ++ks) {
            d[ks * 2]     = *(const f32x4*)(xrow + it * 64 + ks * 32 + quad * 8);
            d[ks * 2 + 1] = *(const f32x4*)(xrow + it * 64 + ks * 32 + quad * 8 + 4);
        }
    };

    // prologue: tile0 convert+write, tile1 loads in flight
    f32x4 x0[4], x1[4];
    loadW(0);
    loadx(0, x0);
    loadx(1, x1);
    asm volatile("s_waitcnt vmcnt(0)" ::: "memory");
    convertWrite(0);
    loadW(1);
    asm volatile("s_waitcnt lgkmcnt(0)" ::: "memory");
    SBAR();

    f32x4 acc[6];
    #pragma unroll
    for (int i = 0; i < 6; ++i) acc[i] = (f32x4){0.f, 0.f, 0.f, 0.f};

    for (int it = 0; it < 16; ++it) {
        const int slot = it % 3;

        float xv[16];
        *(f32x4*)(xv)      = x0[0];
        *(f32x4*)(xv + 4)  = x0[1];
        *(f32x4*)(xv + 8)  = x0[2];
        *(f32x4*)(xv + 12) = x0[3];
        #pragma unroll
        for (int i = 0; i < 4; ++i) x0[i] = x1[i];

        // drain loads issued one interval ago (W(it+1), x(it+1))
        asm volatile("s_waitcnt vmcnt(0)" ::: "memory");

        if (it + 1 < 16) {
            convertWrite((it + 1) % 3);          // write slot (it+1)%3
            if (it + 2 < 16) {                   // issue next loads early
                loadW(it + 2);
                loadx(it + 2, x1);
            }
        }
        asm volatile("s_waitcnt lgkmcnt(0)" ::: "memory");  // ds_writes done
        SBAR();                                  // ONE barrier per iter

        #pragma unroll
        for (int ks = 0; ks < 2; ++ks) {
            bf16x8 ah, al;
            #pragma unroll
            for (int jj = 0; jj < 8; ++jj) {
                float  xf = xv[ks * 8 + jj];
                bf16_t h  = (bf16_t)xf;
                ah[jj] = h;
                al[jj] = (bf16_t)(xf - (float)h);
            }
            #pragma unroll
            for (int nt = 0; nt < 6; ++nt) {
                int gi = ks * 24 + nhalf * 6 + nt;
                bf16x8 bh = *(const bf16x8*)(&Wlds[slot][gi][lane * 8]);
                bf16x8 bl = *(const bf16x8*)(&Wlds[slot][gi + 12][lane * 8]);
                acc[nt] = MFMA16(ah, bh, acc[nt]);
                acc[nt] = MFMA16(ah, bl, acc[nt]);
                acc[nt] = MFMA16(al, bh, acc[nt]);
            }
        }
        // no trailing barrier: slot rotation makes it redundant
    }

    // epilogue: D layout col=lane&15, row=quad*4+reg
    const int rowbase = blockIdx.x * 64 + mhalf * 16 + quad * 4;
    for (int nt = 0; nt < 6; ++nt) {
        int n = (nhalf * 6 + nt) * 16 + l16;
        for (int rr = 0; rr < 4; ++rr) {
            int grow = rowbase + rr;
            int bb = grow >> 11, t = grow & 2047;
            float v  = acc[nt][rr];
            bf16_t h = (bf16_t)v;
            if (n < 64) {
                int off = (bb * T_ + t) * H_ + n;
                qh[off] = h; ql[off] = (bf16_t)(v - (float)h);
            } else if (n < 128) {
                int off = (bb * T_ + t) * H_ + (n - 64);
                kh[off] = h; kl[off] = (bf16_t)(v - (float)h);
            } else {
                vh[(bb * H_ + (n - 128)) * T_ + t] = h;
            }
        }
    }

    // zero Oacc+lacc slice (266240 f32x4 total = 256 blocks x 1040)
    {
        f32x4* Z = zero_dst + (size_t)blockIdx.x * 1040;
        for (int i = tid; i < 1040; i += 512)
            Z[i] = (f32x4){0.f, 0.f, 0.f, 0.f};
    }
}

// ---------------------------------------------------------------------------
// Kernel 2: attention (unchanged R9/R11: raw barriers, counted vmcnt).
// ---------------------------------------------------------------------------
__global__ __launch_bounds__(512, 4) void attn_kernel(
    const bf16_t* __restrict__ qh, const bf16_t* __restrict__ ql,
    const bf16_t* __restrict__ kh, const bf16_t* __restrict__ kl,
    const bf16_t* __restrict__ vh,
    float* __restrict__ Oacc, float* __restrict__ lacc)
{
    __shared__ bf16_t KV[2][3][4096];     // [dbuf][kh|kl|v][64x64] = 48 KB
    __shared__ bf16_t Plds[8][16 * 72];   // per-wave P buffer, 18 KB

    const int tid  = threadIdx.x;
    const int wid  = tid >> 6;
    const int lane = tid & 63;
    const int quad = lane >> 4;
    const int l16  = lane & 15;

    const int b  = blockIdx.x & 7;         // XCD-aligned batch
    const int gp = (blockIdx.x >> 3) & 7;  // pair index
    const int s  = blockIdx.x >> 6;        // j-slice 0..7
    const int gA = gp, gB = 15 - gp;
    const int nA = 2 * gA + 2;             // j-steps of tile A (tile B: 34-nA)

    const int t_nt   = wid >> 1;
    const int t_kk   = wid & 1;
    const int t_l16  = tid & 15;
    const int t_quad = (tid >> 4) & 3;
    const int koff   = (t_nt * 16 + t_l16) * H_ + t_kk * 32 + t_quad * 8;
    const int voff   = (t_nt * 16 + t_l16) * T_ + t_kk * 32 + t_quad * 8;

    auto stage = [&](int j, int bufi) {
        const size_t kbase = (size_t)(b * T_ + 64 * j) * H_;
        GLL16(kh + kbase + koff, &KV[bufi][0][wid * 512]);
        GLL16(kl + kbase + koff, &KV[bufi][1][wid * 512]);
        GLL16(vh + (size_t)b * H_ * T_ + 64 * j + voff, &KV[bufi][2][wid * 512]);
    };

    f32x4  O[4];
    float  rowsum[4];
    bf16x8 aqh[2], aql[2];
    int    gcur = -1;

    auto flushO = [&]() {
        #pragma unroll
        for (int rr = 0; rr < 4; ++rr) {
            int trow = b * T_ + 128 * gcur + 16 * wid + quad * 4 + rr;
            #pragma unroll
            for (int ht = 0; ht < 4; ++ht)
                atomicAdd(Oacc + (size_t)trow * H_ + ht * 16 + l16, O[ht][rr]);
            float s_ = rowsum[rr];
            s_ += __shfl_xor(s_, 1, 64);
            s_ += __shfl_xor(s_, 2, 64);
            s_ += __shfl_xor(s_, 4, 64);
            s_ += __shfl_xor(s_, 8, 64);
            if (l16 == 0) atomicAdd(lacc + trow, s_);
        }
    };

    {
        int u0 = s;
        int j0 = (u0 < nA) ? u0 : (u0 - nA);
        stage(j0, 0);
    }

    int buf = 0;
    for (int u = s; u < 34; u += 8) {
        const int g = (u < nA) ? gA : gB;
        const int j = (u < nA) ? u : (u - nA);

        const int un = u + 8;
        if (un < 34) {
            int jn = (un < nA) ? un : (un - nA);
            stage(jn, buf ^ 1);
            asm volatile("s_waitcnt vmcnt(3)" ::: "memory");
        } else {
            asm volatile("s_waitcnt vmcnt(0)" ::: "memory");
        }
        SBAR();                            // raw: next K/V stays in flight

        if (g != gcur) {
            if (gcur >= 0) flushO();
            gcur = g;
            const size_t qoff = (size_t)(b * T_ + 128 * g + 16 * wid + l16) * H_;
            #pragma unroll
            for (int kk = 0; kk < 2; ++kk) {
                aqh[kk] = *(const bf16x8*)(qh + qoff + kk * 32 + quad * 8);
                aql[kk] = *(const bf16x8*)(ql + qoff + kk * 32 + quad * 8);
            }
            #pragma unroll
            for (int i = 0; i < 4; ++i) { O[i] = (f32x4){0.f,0.f,0.f,0.f}; rowsum[i] = 0.f; }
        }

        const bf16_t* Kh = KV[buf][0];
        const bf16_t* Kl = KV[buf][1];
        f32x4 S[4];
        #pragma unroll
        for (int i = 0; i < 4; ++i) S[i] = (f32x4){0.f,0.f,0.f,0.f};
        #pragma unroll
        for (int nt = 0; nt < 4; ++nt) {
            #pragma unroll
            for (int kk = 0; kk < 2; ++kk) {
                bf16x8 bh = *(const bf16x8*)(Kh + (nt * 2 + kk) * 512 + lane * 8);
                bf16x8 bl = *(const bf16x8*)(Kl + (nt * 2 + kk) * 512 + lane * 8);
                S[nt] = MFMA16(aqh[kk], bh, S[nt]);
                S[nt] = MFMA16(aqh[kk], bl, S[nt]);
                S[nt] = MFMA16(aql[kk], bh, S[nt]);
            }
        }

        bf16_t* Pw = Plds[wid];
        const int rloc = 128 * g + 16 * wid + quad * 4;
        #pragma unroll
        for (int nt = 0; nt < 4; ++nt) {
            int colt = 64 * j + nt * 16 + l16;
            #pragma unroll
            for (int rr = 0; rr < 4; ++rr) {
                float pv = (colt <= rloc + rr)
                         ? __expf(fmaf(S[nt][rr], 0.125f, -20.0f)) : 0.f;
                rowsum[rr] += pv;
                Pw[(quad * 4 + rr) * 72 + nt * 16 + l16] = (bf16_t)pv;
            }
        }

        bf16x8 ap0 = *(const bf16x8*)(Pw + l16 * 72 + quad * 8);
        bf16x8 ap1 = *(const bf16x8*)(Pw + l16 * 72 + 32 + quad * 8);

        const bf16_t* Vt = KV[buf][2];
        #pragma unroll
        for (int ht = 0; ht < 4; ++ht) {
            bf16x8 bv0 = *(const bf16x8*)(Vt + (ht * 2 + 0) * 512 + lane * 8);
            bf16x8 bv1 = *(const bf16x8*)(Vt + (ht * 2 + 1) * 512 + lane * 8);
            O[ht] = MFMA16(ap0, bv0, O[ht]);
            O[ht] = MFMA16(ap1, bv1, O[ht]);
        }

        SBAR();                            // done reading buf before re-stage
        buf ^= 1;
    }
    if (gcur >= 0) flushO();
}

// ---------------------------------------------------------------------------
// Kernel 3: out = Oacc / lacc
// ---------------------------------------------------------------------------
__global__ __launch_bounds__(256) void div_kernel(
    const float* __restrict__ Oacc, const float* __restrict__ lacc,
    float* __restrict__ out)
{
    int i = blockIdx.x * 256 + threadIdx.x;          // f32x4 index, 262144 total
    f32x4 o   = ((const f32x4*)Oacc)[i];
    float inv = 1.0f / lacc[i >> 4];
    ((f32x4*)out)[i] = o * inv;
}

// ---------------------------------------------------------------------------
extern "C" void kernel_launch(void* const* d_in, const int* in_sizes, int n_in,
                              void* d_out, int out_size, void* d_ws, size_t ws_size,
                              hipStream_t stream)
{
    const float* x  = (const float*)d_in[0];
    const float* Wk = (const float*)d_in[1];
    const float* Wq = (const float*)d_in[2];
    const float* Wv = (const float*)d_in[3];
    float* out = (float*)d_out;

    char* ws = (char*)d_ws;
    const size_t QSZ = (size_t)B_ * T_ * H_ * sizeof(bf16_t);  // 2097152
    bf16_t* qh   = (bf16_t*)(ws);
    bf16_t* ql   = (bf16_t*)(ws + 1 * QSZ);
    bf16_t* kh   = (bf16_t*)(ws + 2 * QSZ);
    bf16_t* kl   = (bf16_t*)(ws + 3 * QSZ);
    bf16_t* vh   = (bf16_t*)(ws + 4 * QSZ);
    float*  Oacc = (float*)(ws + 5 * QSZ);                     // 4 MB
    float*  lacc = (float*)(ws + 5 * QSZ + (size_t)B_ * T_ * H_ * 4);

    hipLaunchKernelGGL(proj_kernel, dim3(256), dim3(512), 0, stream,
                       x, Wk, Wq, Wv, qh, ql, kh, kl, vh, (f32x4*)Oacc);
    hipLaunchKernelGGL(attn_kernel, dim3(512), dim3(512), 0, stream,
                       qh, ql, kh, kl, vh, Oacc, lacc);
    hipLaunchKernelGGL(div_kernel, dim3(1024), dim3(256), 0, stream, Oacc, lacc, out);
}